// Round 16
// baseline (28.590 us; speedup 1.0000x reference)
//
#include <hip/hip_runtime.h>

// IIR filter bank: B=16, T=32768, F=30, order 6 (K=7).
// Overlap-and-discard chunking (CHUNK=64, WARM=128).
// R15 = R14 compute/flush structure + PERSISTENT 2-ITEM BLOCKS.
//   Evidence: R10/R11 Occupancy ~15% (~5 waves/CU avg) vs 9 possible;
//   4096 one-shot blocks = 1.78 generations -> dispatch tail + each
//   block's store drain serializes with its slot's next launch.
//   Fix: grid 2048 = 8 blocks/CU EXACTLY (one generation, zero tail,
//   uniform work). Each single-wave block runs items {2bid, 2bid+1}:
//   item0's flush stores are issued with NO vmcnt wait and drain in
//   background while item1 computes (same-wave DS ordering makes ly
//   reuse safe with no extra barrier). lx double-buffered.

#define BB 16
#define TT 32768
#define FF 30
#define KK 7
#define ORD 6
#define CHUNK 64
#define WARM 128
#define CPB 2                  // chunks per item
#define TSPAN (CPB * CHUNK)    // 128 samples per item
#define NBC (TT / TSPAN)       // 256 columns per row
#define YSTR 132               // ly row stride (528B, 16B-aligned)
#define XTILE (WARM + TSPAN)   // 256 floats staged x per item
#define BLK 64                 // ONE wave per block
#define ITEMS 2                // items per persistent block

// Transposed direct-form II step: 13 FMAs, no state shifting.
__device__ __forceinline__ float iir_step(float xv, float st[ORD],
                                          const float bcf[KK],
                                          const float acf[ORD]) {
    float y = fmaf(bcf[0], xv, st[0]);
#pragma unroll
    for (int j = 0; j < ORD - 1; ++j)
        st[j] = fmaf(-acf[j], y, fmaf(bcf[j + 1], xv, st[j + 1]));
    st[ORD - 1] = fmaf(-acf[ORD - 1], y, bcf[KK - 1] * xv);
    return y;
}

__global__ __launch_bounds__(BLK, 1) void iir_persist_kernel(
    const float* __restrict__ x,    // [B][T]
    const float* __restrict__ bs,   // [F][K]
    const float* __restrict__ as_,  // [F][K]
    float* __restrict__ out)        // [B][F][T]
{
    __shared__ __align__(16) float ly[FF * YSTR];       // 15840 B, reused
    __shared__ __align__(16) float lx[ITEMS][XTILE];    //  2048 B dbuf

    const int tid = threadIdx.x;
    const int f  = tid % FF;        // lanes 0-29: cl=0, 30-59: cl=1
    const int cl = tid / FF;
    const bool active = tid < FF * CPB;

    // Coefficients once (shared by both items).
    float bcf[KK], acf[ORD];
    {
        const int fc = active ? f : 0;
        const float inv_a0 = 1.0f / as_[fc * KK];
#pragma unroll
        for (int j = 0; j < KK; ++j) bcf[j] = bs[fc * KK + j] * inv_a0;
#pragma unroll
        for (int j = 0; j < ORD; ++j) acf[j] = as_[fc * KK + 1 + j] * inv_a0;
    }

#pragma unroll
    for (int it2 = 0; it2 < ITEMS; ++it2) {
        const int id  = ITEMS * (int)blockIdx.x + it2;  // work item
        const int b   = id / NBC;
        const int bc  = id % NBC;
        const int bt0 = bc * TSPAN;
        const int xs  = bt0 - WARM;    // negative only for bc==0

        // Cooperative x stage: one float4 per lane; zero-fill t<0 (zero
        // input keeps zero state -> exact head). Writes lx[it2]: does not
        // disturb the other buffer; prior flush already consumed ly.
        {
            const float* __restrict__ xrow = x + b * TT;
            const int t = xs + 4 * tid;
            float4 v = make_float4(0.f, 0.f, 0.f, 0.f);
            if (t >= 0) v = *reinterpret_cast<const float4*>(xrow + t);
            *reinterpret_cast<float4*>(lx[it2] + 4 * tid) = v;
        }
        __syncthreads();   // single-wave block: cheap

        if (active) {
            // Register-stage the lane's whole window: 48 float4 up front
            // (2 distinct addrs per read across wave -> broadcast, free).
            const float4* lx4 = reinterpret_cast<const float4*>(lx[it2]);
            const int g0 = 16 * cl;
            float4 va[16], vb[16], vc[16];
#pragma unroll
            for (int k = 0; k < 16; ++k) va[k] = lx4[g0 + k];
#pragma unroll
            for (int k = 0; k < 16; ++k) vb[k] = lx4[g0 + 16 + k];
#pragma unroll
            for (int k = 0; k < 16; ++k) vc[k] = lx4[g0 + 32 + k];
            // Keep the reads hoisted; consume loops below are pure-VGPR.
            __builtin_amdgcn_sched_barrier(0);

            float st[ORD];
#pragma unroll
            for (int j = 0; j < ORD; ++j) st[j] = 0.0f;

            // Warm-up: 128 steps from registers, zero memory stalls.
#pragma unroll
            for (int k = 0; k < 16; ++k) {
                iir_step(va[k].x, st, bcf, acf);
                iir_step(va[k].y, st, bcf, acf);
                iir_step(va[k].z, st, bcf, acf);
                iir_step(va[k].w, st, bcf, acf);
            }
#pragma unroll
            for (int k = 0; k < 16; ++k) {
                iir_step(vb[k].x, st, bcf, acf);
                iir_step(vb[k].y, st, bcf, acf);
                iir_step(vb[k].z, st, bcf, acf);
                iir_step(vb[k].w, st, bcf, acf);
            }

            // Output: 64 steps, one ds_write_b128 per 4 samples.
            // Same-wave DS ordering: these writes cannot pass the prior
            // item's flush ds_reads -> ly reuse is race-free.
            float* lyc = ly + f * YSTR + cl * CHUNK;
#pragma unroll
            for (int k = 0; k < 16; ++k) {
                float4 y;
                y.x = iir_step(vc[k].x, st, bcf, acf);
                y.y = iir_step(vc[k].y, st, bcf, acf);
                y.z = iir_step(vc[k].z, st, bcf, acf);
                y.w = iir_step(vc[k].w, st, bcf, acf);
                *reinterpret_cast<float4*>(lyc + 4 * k) = y;
            }
        }
        __syncthreads();

        // Flush: 960 float4, 15 per lane; lanes 0-31 row 2i, lanes 32-63
        // row 2i+1 -> two contiguous 512B runs per instruction, full 64B
        // lines. Stores issue with NO vmcnt wait: they drain under the
        // next item's compute (overlap that one-shot blocks never got).
        float* __restrict__ obase = out + b * FF * TT + bt0;
#pragma unroll
        for (int i = 0; i < (FF * TSPAN / 4) / BLK; ++i) {  // 15
            const int j  = tid + BLK * i;
            const int fr = j >> 5;            // 32 float4 per row
            const int tl = (j & 31) << 2;
            const float4 v =
                *reinterpret_cast<const float4*>(ly + fr * YSTR + tl);
            *reinterpret_cast<float4*>(obase + fr * TT + tl) = v;
        }
    }
}

extern "C" void kernel_launch(void* const* d_in, const int* in_sizes, int n_in,
                              void* d_out, int out_size, void* d_ws,
                              size_t ws_size, hipStream_t stream) {
    const float* x   = (const float*)d_in[0];
    const float* bs  = (const float*)d_in[1];
    const float* as_ = (const float*)d_in[2];
    float* out = (float*)d_out;

    const int grid = (BB * NBC) / ITEMS;  // 2048 blocks = 8/CU, 1 generation
    hipLaunchKernelGGL(iir_persist_kernel, dim3(grid), dim3(BLK), 0, stream,
                       x, bs, as_, out);
}